// Round 2
// baseline (235.713 us; speedup 1.0000x reference)
//
#include <hip/hip_runtime.h>

// GridSpatialIntegral: out[:,0] = cumsum_x(in[:,0]); out[:,1] = cumsum_y(in[:,1])
// [B=64, C=2, 512, 512] fp32. Memory-bound: 128 MiB in + 128 MiB out, floor ~41 us.

#define W 512
#define NB 64

// ---------------- channel 0: inclusive scan along contiguous x ----------------
// One wave per 512-float row; 4 waves (256 threads) per block; 8192 blocks.
// Low VGPR -> 32 waves/CU.
__global__ __launch_bounds__(256)
void gsi_x_kernel(const float* __restrict__ in, float* __restrict__ out) {
    const int wave = threadIdx.x >> 6;
    const int lane = threadIdx.x & 63;
    const int row  = (blockIdx.x << 2) + wave;       // 0..32767
    const int b    = row >> 9;
    const int y    = row & 511;
    const size_t base = (size_t)b * (2 * W * W) + (size_t)y * W;   // channel 0

    const float4* ip = (const float4*)(in + base);
    float4*       op = (float4*)(out + base);

    float4 v0 = ip[lane * 2];
    float4 v1 = ip[lane * 2 + 1];

    float e0 = v0.x;
    float e1 = e0 + v0.y;
    float e2 = e1 + v0.z;
    float e3 = e2 + v0.w;
    float e4 = e3 + v1.x;
    float e5 = e4 + v1.y;
    float e6 = e5 + v1.z;
    float e7 = e6 + v1.w;

    float s = e7;
    #pragma unroll
    for (int off = 1; off < 64; off <<= 1) {
        float t = __shfl_up(s, off, 64);
        if (lane >= off) s += t;
    }
    const float offset = s - e7;   // exclusive prefix of per-lane totals

    op[lane * 2]     = make_float4(e0 + offset, e1 + offset, e2 + offset, e3 + offset);
    op[lane * 2 + 1] = make_float4(e4 + offset, e5 + offset, e6 + offset, e7 + offset);
}

// ---------------- channel 1: inclusive scan along strided y ----------------
// Block = 1024 threads = 32 tx * 32 ty. Tile = 128 columns x 512 rows.
// Each thread: float4 (4 columns) x 16 rows in registers (64 data VGPRs).
// Every global access: lanes 0-31 cover 512 contiguous bytes (float4/lane).
// 256 blocks -> exactly 1 block/CU (launch_bounds 1024,4 => <=128 VGPR).
__global__ __launch_bounds__(1024, 4)
void gsi_y_kernel(const float* __restrict__ in, float* __restrict__ out) {
    __shared__ float4 seg[32][32];
    const int tx = threadIdx.x & 31;         // float4-column within tile
    const int ty = threadIdx.x >> 5;         // y-segment of 16 rows
    const int b  = blockIdx.x >> 2;
    const int x0 = (blockIdx.x & 3) << 7;    // 128-column tile

    const size_t base = (size_t)b * (2 * W * W) + (size_t)(W * W)  // channel 1
                      + (size_t)(ty * 16) * W + (size_t)x0 + (size_t)(tx * 4);
    const float4* ip = (const float4*)(in + base);
    float4*       op = (float4*)(out + base);
    // row stride in float4 units: W/4 = 128

    float4 d[16];
    float4 sum = make_float4(0.f, 0.f, 0.f, 0.f);
    #pragma unroll
    for (int k = 0; k < 16; ++k) {
        d[k] = ip[k * 128];
        sum.x += d[k].x; sum.y += d[k].y; sum.z += d[k].z; sum.w += d[k].w;
    }

    seg[ty][tx] = sum;
    __syncthreads();

    float4 acc = make_float4(0.f, 0.f, 0.f, 0.f);
    for (int j = 0; j < ty; ++j) {
        float4 t = seg[j][tx];
        acc.x += t.x; acc.y += t.y; acc.z += t.z; acc.w += t.w;
    }

    #pragma unroll
    for (int k = 0; k < 16; ++k) {
        acc.x += d[k].x; acc.y += d[k].y; acc.z += d[k].z; acc.w += d[k].w;
        op[k * 128] = acc;
    }
}

extern "C" void kernel_launch(void* const* d_in, const int* in_sizes, int n_in,
                              void* d_out, int out_size, void* d_ws, size_t ws_size,
                              hipStream_t stream) {
    const float* in  = (const float*)d_in[0];
    float*       out = (float*)d_out;
    (void)in_sizes; (void)n_in; (void)out_size; (void)d_ws; (void)ws_size;

    // Heavier-per-block kernel first (better tail behavior under replay).
    gsi_y_kernel<<<dim3(NB * 4), dim3(1024), 0, stream>>>(in, out);
    gsi_x_kernel<<<dim3(NB * 512 / 4), dim3(256), 0, stream>>>(in, out);
}

// Round 4
// 227.484 us; speedup vs baseline: 1.0362x; 1.0362x over previous
//
#include <hip/hip_runtime.h>

// GridSpatialIntegral: out[:,0] = cumsum_x(in[:,0]); out[:,1] = cumsum_y(in[:,1])
// [B=64, C=2, 512, 512] fp32. Memory-bound: 134 MB read + 134 MB write, floor ~41 us.
//
// Single fused launch, 512-thread blocks (8 waves):
//   blocks [0, 512):     channel 1 (y-scan) — 64-col x 512-row tile per block
//   blocks [512, 4608):  channel 0 (x-scan) — 8 rows per block, 1 wave per row
// y-blocks first so the long-pole work dispatches early; x/y blocks co-resident
// per CU hide each other's memory latency. Nontemporal hints: pure streaming.

#define W 512
#define NB 64
#define YBLOCKS (NB * 8)          // 512
#define XBLOCKS (NB * W / 8)      // 4096

typedef float v4f __attribute__((ext_vector_type(4)));   // clang vector: NT-builtin OK

__global__ __launch_bounds__(512)
void gsi_kernel(const float* __restrict__ in, float* __restrict__ out) {
    __shared__ v4f seg[32][16];    // y-path segment sums (8 KB)
    const int tid = threadIdx.x;

    if (blockIdx.x < YBLOCKS) {
        // -------- channel 1: inclusive scan along strided y --------
        // 512 threads = 16 tx (float4 cols) x 32 ty (16-row segments).
        const int bi = blockIdx.x;
        const int b  = bi >> 3;
        const int x0 = (bi & 7) << 6;        // 64-column tile
        const int tx = tid & 15;
        const int ty = tid >> 4;

        const size_t base = (size_t)b * (2 * W * W) + (size_t)(W * W)
                          + (size_t)(ty * 16) * W + (size_t)x0 + (size_t)(tx * 4);
        const v4f* ip = (const v4f*)(in + base);
        v4f*       op = (v4f*)(out + base);
        // row stride in v4f units: W/4 = 128

        v4f d[16];
        v4f sum = (v4f)(0.f);
        #pragma unroll
        for (int k = 0; k < 16; ++k) {
            d[k] = __builtin_nontemporal_load(&ip[k * 128]);
            sum += d[k];
        }

        seg[ty][tx] = sum;
        __syncthreads();

        v4f acc = (v4f)(0.f);
        for (int j = 0; j < ty; ++j) acc += seg[j][tx];

        #pragma unroll
        for (int k = 0; k < 16; ++k) {
            acc += d[k];
            __builtin_nontemporal_store(acc, &op[k * 128]);
        }
    } else {
        // -------- channel 0: inclusive scan along contiguous x --------
        const int wave = tid >> 6;                       // 0..7
        const int lane = tid & 63;
        const int row  = ((blockIdx.x - YBLOCKS) << 3) + wave;   // 0..32767
        const int b    = row >> 9;
        const int y    = row & 511;
        const size_t base = (size_t)b * (2 * W * W) + (size_t)y * W;

        const v4f* ip = (const v4f*)(in + base);
        v4f*       op = (v4f*)(out + base);

        v4f v0 = __builtin_nontemporal_load(&ip[lane * 2]);
        v4f v1 = __builtin_nontemporal_load(&ip[lane * 2 + 1]);

        float e0 = v0.x;
        float e1 = e0 + v0.y;
        float e2 = e1 + v0.z;
        float e3 = e2 + v0.w;
        float e4 = e3 + v1.x;
        float e5 = e4 + v1.y;
        float e6 = e5 + v1.z;
        float e7 = e6 + v1.w;

        float s = e7;
        #pragma unroll
        for (int off = 1; off < 64; off <<= 1) {
            float t = __shfl_up(s, off, 64);
            if (lane >= off) s += t;
        }
        const float offset = s - e7;   // exclusive prefix of per-lane totals

        v4f o0 = {e0 + offset, e1 + offset, e2 + offset, e3 + offset};
        v4f o1 = {e4 + offset, e5 + offset, e6 + offset, e7 + offset};
        __builtin_nontemporal_store(o0, &op[lane * 2]);
        __builtin_nontemporal_store(o1, &op[lane * 2 + 1]);
    }
}

extern "C" void kernel_launch(void* const* d_in, const int* in_sizes, int n_in,
                              void* d_out, int out_size, void* d_ws, size_t ws_size,
                              hipStream_t stream) {
    const float* in  = (const float*)d_in[0];
    float*       out = (float*)d_out;
    (void)in_sizes; (void)n_in; (void)out_size; (void)d_ws; (void)ws_size;
    gsi_kernel<<<dim3(YBLOCKS + XBLOCKS), dim3(512), 0, stream>>>(in, out);
}